// Round 8
// baseline (413.396 us; speedup 1.0000x reference)
//
#include <hip/hip_runtime.h>
#include <hip/hip_bf16.h>
#include <math.h>

#define DIM 256
#define SBS 256
#define SIT 16           // scan items per thread -> 4096 per block
#define NT   300000
#define NTET 150000

typedef __attribute__((ext_vector_type(8))) short          bf16x8;
typedef __attribute__((ext_vector_type(8))) unsigned short u16x8;
typedef __attribute__((ext_vector_type(4))) float          f32x4;

__device__ inline float b2f(unsigned short u) {
    union { unsigned int i; float f; } c; c.i = ((unsigned int)u) << 16; return c.f;
}
__device__ inline unsigned short f2b(float f) {
    __hip_bfloat16 h = __float2bfloat16(f);
    return *reinterpret_cast<unsigned short*>(&h);
}
__device__ inline short f2bs(float f) { return (short)f2b(f); }
__device__ inline bool bmget(const unsigned* bm, int i) {
    return (bm[i >> 5] >> (i & 31)) & 1u;
}
// async global->LDS 16B: per-lane dest must equal wave-uniform base + lane*16
__device__ inline void gll16(const void* g, void* l) {
    __builtin_amdgcn_global_load_lds(
        (const __attribute__((address_space(1))) unsigned int*)g,
        (__attribute__((address_space(3))) unsigned int*)l, 16, 0, 0);
}

// ================= fused weight cast: 3x [256,256] fp32 -> bf16 =================
__global__ __launch_bounds__(256) void k_cast3(
    const float* __restrict__ w2, const float* __restrict__ w3,
    const float* __restrict__ wt, unsigned short* __restrict__ out)
{
    int i = (blockIdx.x * 256 + threadIdx.x) * 4;      // < 196608
    const float* src; int l;
    if (i < 65536)       { src = w2; l = i; }
    else if (i < 131072) { src = w3; l = i - 65536; }
    else                 { src = wt; l = i - 131072; }
    float4 v = *(const float4*)(src + l);
    ushort4 o; o.x = f2b(v.x); o.y = f2b(v.y); o.z = f2b(v.z); o.w = f2b(v.w);
    *(ushort4*)(out + i) = o;
}

// ================= bitmap marking =================
__global__ __launch_bounds__(256) void k_mark(
    const int* __restrict__ trip, unsigned* __restrict__ bm, int B)
{
    int i = blockIdx.x * 256 + threadIdx.x;
    if (i < 2 * B) {
        int ent = trip[(i >> 1) * 3 + ((i & 1) ? 2 : 0)];
        atomicOr(&bm[ent >> 5], 1u << (ent & 31));
    }
}

__global__ __launch_bounds__(256) void k_markf(
    const int* __restrict__ mi, const int* __restrict__ ci,
    const unsigned* __restrict__ bmIn, unsigned* __restrict__ bmOut, int n)
{
    int e = blockIdx.x * 256 + threadIdx.x;
    if (e < n && bmget(bmIn, ci[e])) {
        int m = mi[e];
        unsigned msk = 1u << (m & 31);
        if (!(bmOut[m >> 5] & msk)) atomicOr(&bmOut[m >> 5], msk);
    }
}

__global__ __launch_bounds__(256) void k_bits(
    const unsigned* __restrict__ bm, int* __restrict__ out, int n)
{
    int i = blockIdx.x * 256 + threadIdx.x;
    if (i < n) out[i] = (bm[i >> 5] >> (i & 31)) & 1u;
}

// ================= concatenated count / scan / place =================
__global__ __launch_bounds__(256) void k_count_all(
    const int* __restrict__ et, const int* __restrict__ tt, const int* __restrict__ etet,
    const unsigned* __restrict__ bmTri, const unsigned* __restrict__ bmTet,
    const unsigned* __restrict__ bmEnt, int* __restrict__ cnt,
    int ET, int TT, int ETET)
{
    int e = blockIdx.x * 256 + threadIdx.x;
    if (e < ET) {
        int d = et[ET + e];
        if (bmget(bmTri, d)) atomicAdd(&cnt[d], 1);
    } else if (e < ET + TT) {
        int i = e - ET;
        int d = tt[TT + i];
        if (bmget(bmTet, d)) atomicAdd(&cnt[NT + d], 1);
    } else if (e < ET + TT + ETET) {
        int i = e - ET - TT;
        int d = etet[i];
        if (bmget(bmEnt, d)) atomicAdd(&cnt[NT + NTET + d], 1);
    }
}

__global__ __launch_bounds__(SBS) void k_scan_block(
    const int* __restrict__ cnt, int* __restrict__ rowOff,
    int* __restrict__ blockSums, int n)
{
    __shared__ int lds[SBS];
    const int t = threadIdx.x;
    const int tbase = blockIdx.x * SBS * SIT + t * SIT;
    int v[SIT]; int tsum = 0;
    #pragma unroll
    for (int i = 0; i < SIT; ++i) {
        int idx = tbase + i;
        v[i] = (idx < n) ? cnt[idx] : 0;
        tsum += v[i];
    }
    lds[t] = tsum;
    __syncthreads();
    #pragma unroll
    for (int off = 1; off < SBS; off <<= 1) {
        int y = (t >= off) ? lds[t - off] : 0;
        __syncthreads();
        lds[t] += y;
        __syncthreads();
    }
    int incl = lds[t];
    int run = incl - tsum;
    #pragma unroll
    for (int i = 0; i < SIT; ++i) {
        int idx = tbase + i;
        if (idx < n) rowOff[idx] = run;
        run += v[i];
    }
    if (t == SBS - 1) blockSums[blockIdx.x] = incl;
}

__global__ __launch_bounds__(SBS) void k_scan_sums(int* __restrict__ bs, int nb)
{
    __shared__ int lds[SBS];
    const int t = threadIdx.x;
    int v = (t < nb) ? bs[t] : 0;
    lds[t] = v;
    __syncthreads();
    #pragma unroll
    for (int off = 1; off < SBS; off <<= 1) {
        int y = (t >= off) ? lds[t - off] : 0;
        __syncthreads();
        lds[t] += y;
        __syncthreads();
    }
    if (t < nb) {
        bs[t] = lds[t] - v;
        if (t == nb - 1) bs[nb] = lds[t];
    }
}

__global__ __launch_bounds__(256) void k_scan_add(
    int* __restrict__ rowOff, int* __restrict__ cursor,
    const int* __restrict__ bs, int n, int nb, int ncur)
{
    int i = blockIdx.x * 256 + threadIdx.x;
    if (i < n) {
        int v = rowOff[i] + bs[i / (SBS * SIT)];
        rowOff[i] = v;
        if (i < ncur) cursor[i] = v;
    }
    if (i == 0) rowOff[n] = bs[nb];
}

__global__ __launch_bounds__(256) void k_place_all(
    const int* __restrict__ et, const int* __restrict__ tt, const int* __restrict__ etet,
    const unsigned* __restrict__ bmTri, const unsigned* __restrict__ bmTet,
    const unsigned* __restrict__ bmEnt, int* __restrict__ cursor,
    int* __restrict__ sorted, int ET, int TT, int ETET)
{
    int e = blockIdx.x * 256 + threadIdx.x;
    if (e < ET) {
        int d = et[ET + e];
        if (bmget(bmTri, d)) sorted[atomicAdd(&cursor[d], 1)] = et[e];
    } else if (e < ET + TT) {
        int i = e - ET;
        int d = tt[TT + i];
        if (bmget(bmTet, d)) sorted[atomicAdd(&cursor[NT + d], 1)] = tt[i];
    } else if (e < ET + TT + ETET) {
        int i = e - ET - TT;
        int d = etet[i];
        if (bmget(bmEnt, d)) sorted[atomicAdd(&cursor[NT + NTET + d], 1)] = etet[ETET + i];
    }
}

// ================= gather-aggregate: half-wave (32 lanes x 16B) per dst row =================
template<int EPI>
__global__ __launch_bounds__(256) void k_gather(
    const unsigned short* __restrict__ src, const int* __restrict__ sorted,
    const int* __restrict__ rowOff, const float* __restrict__ bias,
    const float* __restrict__ E, const float* __restrict__ alpha,
    const unsigned* __restrict__ bm, const int* __restrict__ cmpOff,
    void* __restrict__ out, int ndst)
{
    const int g    = (blockIdx.x * 256 + threadIdx.x) >> 6;
    const int lane = threadIdx.x & 63;
    const int half = lane >> 5;
    const int hl   = lane & 31;
    const int d    = g * 2 + half;
    const bool need = (d < ndst) && bmget(bm, d);
    if (!__any(need)) return;
    const int cmpBase = (EPI >= 1) ? cmpOff[0] : 0;
    int e0 = 0, e1 = 0;
    if (need) { e0 = rowOff[d]; e1 = rowOff[d + 1]; }
    float acc[8] = {0.f, 0.f, 0.f, 0.f, 0.f, 0.f, 0.f, 0.f};
    for (int p = e0; p < e1; p += 4) {
        u16x8 u[4]; float gt[4];
        #pragma unroll
        for (int j = 0; j < 4; ++j) {
            int ee = p + j;
            int ec = (ee < e1) ? ee : (e1 - 1);
            int s  = sorted[ec];
            if (EPI == 2) s = cmpOff[s] - cmpBase;
            u[j]  = *(const u16x8*)(src + (size_t)s * DIM + hl * 8);
            gt[j] = (ee < e1) ? 1.0f : 0.0f;
        }
        #pragma unroll
        for (int j = 0; j < 4; ++j)
            #pragma unroll
            for (int k = 0; k < 8; ++k)
                acc[k] += gt[j] * b2f(u[j][k]);
    }
    float inv = 1.0f / fmaxf((float)(e1 - e0), 1.0f);
    #pragma unroll
    for (int k = 0; k < 8; ++k) acc[k] *= inv;
    if (EPI == 0) {
        float4 bl = *(const float4*)(bias + hl * 8);
        float4 bh = *(const float4*)(bias + hl * 8 + 4);
        float bb[8] = {bl.x, bl.y, bl.z, bl.w, bh.x, bh.y, bh.z, bh.w};
        if (need) {
            u16x8 o;
            #pragma unroll
            for (int k = 0; k < 8; ++k) o[k] = f2b(fmaxf(acc[k] + bb[k], 0.f));
            *(u16x8*)((unsigned short*)out + (size_t)d * DIM + hl * 8) = o;
        }
    } else if (EPI == 1) {
        if (need) {
            int cd = cmpOff[d] - cmpBase;
            u16x8 o;
            #pragma unroll
            for (int k = 0; k < 8; ++k) o[k] = f2b(acc[k]);
            *(u16x8*)((unsigned short*)out + (size_t)cd * DIM + hl * 8) = o;
        }
    } else {
        float a0 = alpha[0], a1v = alpha[1];
        float mx = fmaxf(a0, a1v);
        float x0 = expf(a0 - mx), x1 = expf(a1v - mx);
        float w0 = x0 / (x0 + x1), w1 = x1 / (x0 + x1);
        if (need) {
            const float* er = E + (size_t)d * DIM + hl * 8;
            float4 el = *(const float4*)er;
            float4 eh = *(const float4*)(er + 4);
            float4 o0, o1;
            o0.x = w0 * el.x + w1 * acc[0]; o0.y = w0 * el.y + w1 * acc[1];
            o0.z = w0 * el.z + w1 * acc[2]; o0.w = w0 * el.w + w1 * acc[3];
            o1.x = w0 * eh.x + w1 * acc[4]; o1.y = w0 * eh.y + w1 * acc[5];
            o1.z = w0 * eh.z + w1 * acc[6]; o1.w = w0 * eh.w + w1 * acc[7];
            float* orow = (float*)out + (size_t)d * DIM + hl * 8;
            *(float4*)orow = o0;
            *(float4*)(orow + 4) = o1;
        }
    }
}

// ================= bf16 MFMA GEMM via async global_load_lds staging =================
// Tile 128x128, BK=64, 256 threads = 4 waves (2x2 of 64x64).
// Staging: global_load_lds width 16, LINEAR LDS dest; bank-conflict swizzle is
// applied on the GLOBAL SOURCE piece index (rule #21: inverse-swz source + swz read).
//   A fp32 tile [128 rows][16 pieces x16B]: slot s of row r holds global piece s^(r&15)
//   A bf16 / W  [128 rows][ 8 pieces x16B]: slot s of row r holds global piece s^(r&7)
// Fragment reads apply the same involution; fp32 A-frags convert to bf16 post-read.
template<bool AF32, bool RELU, bool BIAS, bool DYNM>
__global__ __launch_bounds__(256) void k_gemm_mfma(
    const void* __restrict__ Ap, const unsigned short* __restrict__ Wb,
    const float* __restrict__ bias, unsigned short* __restrict__ Cp,
    int Ms, const int* __restrict__ cmpOff)
{
    int M = Ms;
    if (DYNM) M = cmpOff[NTET] - cmpOff[0];
    const int m0 = blockIdx.x * 128;
    if (m0 >= M) return;
    __shared__ __align__(16) char smem[AF32 ? 49152 : 32768];
    char* AsB = smem;
    char* WsB = smem + (AF32 ? 32768 : 16384);
    const int tid  = threadIdx.x;
    const int n0   = blockIdx.y * 128;
    const int wid  = tid >> 6, lane = tid & 63;
    const int wr   = wid >> 1, wc = wid & 1;
    const int fr   = lane & 15;
    const int fc   = lane >> 4;
    // source-swizzle piece indices (constant per thread)
    const int gA = (tid & 15) ^ ((tid >> 4) & 15);   // fp32 A: 16 pieces/row
    const int gW = (tid & 7)  ^ ((tid >> 3) & 7);    // bf16: 8 pieces/row

    f32x4 acc[4][4] = {};
    for (int k0 = 0; k0 < DIM; k0 += 64) {
        __syncthreads();             // prior iter's reads done before overwrite
        if (AF32) {
            #pragma unroll
            for (int it = 0; it < 8; ++it) {
                int r  = it * 16 + (tid >> 4);
                int gm = m0 + r; if (gm >= M) gm = M - 1;
                const float* srcp = (const float*)Ap + (size_t)gm * DIM + k0 + gA * 4;
                gll16(srcp, AsB + (size_t)(it * 256 + tid) * 16);
            }
        } else {
            #pragma unroll
            for (int it = 0; it < 4; ++it) {
                int r  = it * 32 + (tid >> 3);
                int gm = m0 + r; if (gm >= M) gm = M - 1;
                const unsigned short* srcp = (const unsigned short*)Ap + (size_t)gm * DIM + k0 + gW * 8;
                gll16(srcp, AsB + (size_t)(it * 256 + tid) * 16);
            }
        }
        #pragma unroll
        for (int it = 0; it < 4; ++it) {
            int n = it * 32 + (tid >> 3);
            const unsigned short* srcp = Wb + (size_t)(n0 + n) * DIM + k0 + gW * 8;
            gll16(srcp, WsB + (size_t)(it * 256 + tid) * 16);
        }
        __syncthreads();             // drains vmcnt -> staged data visible
        #pragma unroll
        for (int kk = 0; kk < 2; ++kk) {
            bf16x8 aF[4], bF[4];
            #pragma unroll
            for (int i = 0; i < 4; ++i) {
                int ar = wr * 64 + i * 16 + fr;
                if (AF32) {
                    int p0 = kk * 8 + fc * 2;
                    const char* rb = AsB + ar * 256;
                    float4 lo = *(const float4*)(rb + ((p0       ^ (ar & 15)) * 16));
                    float4 hi = *(const float4*)(rb + (((p0 + 1) ^ (ar & 15)) * 16));
                    bf16x8 a;
                    a[0] = f2bs(lo.x); a[1] = f2bs(lo.y); a[2] = f2bs(lo.z); a[3] = f2bs(lo.w);
                    a[4] = f2bs(hi.x); a[5] = f2bs(hi.y); a[6] = f2bs(hi.z); a[7] = f2bs(hi.w);
                    aF[i] = a;
                } else {
                    int p = kk * 4 + fc;
                    aF[i] = *(const bf16x8*)(AsB + ar * 128 + ((p ^ (ar & 7)) * 16));
                }
                int wn = wc * 64 + i * 16 + fr;
                int pw = kk * 4 + fc;
                bF[i] = *(const bf16x8*)(WsB + wn * 128 + ((pw ^ (wn & 7)) * 16));
            }
            #pragma unroll
            for (int i = 0; i < 4; ++i)
                #pragma unroll
                for (int j = 0; j < 4; ++j)
                    acc[i][j] = __builtin_amdgcn_mfma_f32_16x16x32_bf16(
                        aF[i], bF[j], acc[i][j], 0, 0, 0);
        }
    }
    const int cnb   = n0 + wc * 64 + fr;
    const int rbase = m0 + wr * 64 + fc * 4;
    #pragma unroll
    for (int j = 0; j < 4; ++j) {
        float bv = BIAS ? bias[cnb + j * 16] : 0.0f;
        #pragma unroll
        for (int i = 0; i < 4; ++i) {
            #pragma unroll
            for (int q = 0; q < 4; ++q) {
                int m = rbase + i * 16 + q;
                if (m < M) {
                    float v = acc[i][j][q] + bv;
                    if (RELU) v = fmaxf(v, 0.f);
                    Cp[(size_t)m * DIM + cnb + j * 16] = f2b(v);
                }
            }
        }
    }
}

// ================= TransE score =================
__global__ __launch_bounds__(256) void k_score(
    const float* __restrict__ V, const float* __restrict__ R,
    const int* __restrict__ triples, const float* __restrict__ gamma,
    float* __restrict__ out, int B)
{
    int t    = (blockIdx.x * 256 + threadIdx.x) >> 6;
    int lane = threadIdx.x & 63;
    if (t >= B) return;
    int h  = triples[t * 3 + 0];
    int r  = triples[t * 3 + 1];
    int tl = triples[t * 3 + 2];
    float4 vh = *(const float4*)(V + (size_t)h  * DIM + lane * 4);
    float4 vr = *(const float4*)(R + (size_t)r  * DIM + lane * 4);
    float4 vt = *(const float4*)(V + (size_t)tl * DIM + lane * 4);
    float dx = vh.x + vr.x - vt.x;
    float dy = vh.y + vr.y - vt.y;
    float dz = vh.z + vr.z - vt.z;
    float dw = vh.w + vr.w - vt.w;
    float s = dx * dx + dy * dy + dz * dz + dw * dw;
    #pragma unroll
    for (int off = 32; off > 0; off >>= 1) s += __shfl_xor(s, off);
    if (lane == 0) out[t] = gamma[0] - sqrtf(s);
}

extern "C" void kernel_launch(void* const* d_in, const int* in_sizes, int n_in,
                              void* d_out, int out_size, void* d_ws, size_t ws_size,
                              hipStream_t stream)
{
    const float* E      = (const float*)d_in[0];
    const float* R      = (const float*)d_in[1];
    const float* lin2_w = (const float*)d_in[2];
    const float* lin2_b = (const float*)d_in[3];
    const float* lin3_w = (const float*)d_in[4];
    const float* lin3_b = (const float*)d_in[5];
    const float* t2e_w  = (const float*)d_in[6];
    const float* t2e_b  = (const float*)d_in[7];
    const float* alpha  = (const float*)d_in[8];
    const float* gamma  = (const float*)d_in[9];
    const int*   et     = (const int*)d_in[10];
    const int*   tt     = (const int*)d_in[11];
    const int*   etet   = (const int*)d_in[12];
    const int*   trip   = (const int*)d_in[13];

    const int NE    = in_sizes[0] / DIM;          // 100000
    const int ET    = in_sizes[10] / 2;           // 900000
    const int TT    = in_sizes[11] / 2;           // 600000
    const int ETET  = in_sizes[12] / 2;           // 600000
    const int B     = in_sizes[13] / 3;           // 8192
    const int NTOT  = NT + NTET + NE;             // 550000
    const int NTOT2 = NTOT + NTET;                // 700000 (+ tet bits segment)
    const int ETOT  = ET + TT + ETET;             // 2.1M

    // ---- workspace layout (~272 MB) ----
    char* ws = (char*)d_ws;
    const size_t P1  = (size_t)NE * DIM * 4;
    const size_t IDX = P1 + (size_t)NT * DIM * 2;
    unsigned short* EW      = (unsigned short*)ws;
    unsigned short* tetAgg  = (unsigned short*)ws;
    float*          V       = (float*)ws;
    unsigned short* triEmb  = (unsigned short*)(ws + P1);
    unsigned short* tetEmb  = (unsigned short*)(ws + P1);
    unsigned short* tetProj = (unsigned short*)(ws + P1) + (size_t)NTET * DIM;
    size_t off = IDX;
    int* sortedAll = (int*)(ws + off); off += (size_t)ETOT * 4;
    int* rowOffAll = (int*)(ws + off); off += ((size_t)(NTOT2 + 1) * 4 + 15) & ~15ull;
    int* cursorAll = (int*)(ws + off); off += (size_t)NTOT * 4;
    int* blockSums = (int*)(ws + off); off += 1040;
    unsigned short* Wb = (unsigned short*)(ws + off); off += 3 * 131072;
    char* zbase = ws + off;
    int*      cntAll = (int*)(ws + off);      off += (size_t)NTOT2 * 4;
    unsigned* bmEnt  = (unsigned*)(ws + off); off += ((size_t)(NE   + 31) / 32) * 4;
    unsigned* bmTet  = (unsigned*)(ws + off); off += ((size_t)(NTET + 31) / 32) * 4;
    unsigned* bmTri  = (unsigned*)(ws + off); off += ((size_t)(NT   + 31) / 32) * 4;
    size_t zsize = (size_t)(ws + off - zbase);
    if (ws_size < off) return;

    unsigned short* W2b = Wb;
    unsigned short* W3b = Wb + 65536;
    unsigned short* Wtb = Wb + 131072;
    int* cmpOff = rowOffAll + NTOT;               // tet -> compact row map (prefix)

    // ---- upfront: zero index region, cast weights, big GEMM on E ----
    hipMemsetAsync(zbase, 0, zsize, stream);
    k_cast3<<<192, 256, 0, stream>>>(lin2_w, lin3_w, t2e_w, Wb);
    dim3 gE((NE + 127) / 128, 2);
    k_gemm_mfma<true, false, false, false><<<gE, 256, 0, stream>>>(
        E, W2b, nullptr, EW, NE, nullptr);

    // ---- bitmaps: needEnt <- triples; needTet <- etet|needEnt; needTri <- tt|needTet ----
    k_mark<<<(2 * B + 255) / 256, 256, 0, stream>>>(trip, bmEnt, B);
    k_markf<<<(ETET + 255) / 256, 256, 0, stream>>>(etet + ETET, etet, bmEnt, bmTet, ETET);
    k_markf<<<(TT + 255) / 256, 256, 0, stream>>>(tt, tt + TT, bmTet, bmTri, TT);
    k_bits<<<(NTET + 255) / 256, 256, 0, stream>>>(bmTet, cntAll + NTOT, NTET);

    // ---- concatenated count / scan / place (edges + tet-bits segment) ----
    k_count_all<<<(ETOT + 255) / 256, 256, 0, stream>>>(
        et, tt, etet, bmTri, bmTet, bmEnt, cntAll, ET, TT, ETET);
    int nb = (NTOT2 + SBS * SIT - 1) / (SBS * SIT);
    k_scan_block<<<nb, SBS, 0, stream>>>(cntAll, rowOffAll, blockSums, NTOT2);
    k_scan_sums<<<1, SBS, 0, stream>>>(blockSums, nb);
    k_scan_add<<<(NTOT2 + 255) / 256, 256, 0, stream>>>(rowOffAll, cursorAll,
                                                        blockSums, NTOT2, nb, NTOT);
    k_place_all<<<(ETOT + 255) / 256, 256, 0, stream>>>(
        et, tt, etet, bmTri, bmTet, bmEnt, cursorAll, sortedAll, ET, TT, ETET);

    // ---- stage A: triEmb = relu(mean_et(EW) + b2)  [needTri only] ----
    k_gather<0><<<(NT + 7) / 8, 256, 0, stream>>>(EW, sortedAll, rowOffAll, lin2_b,
                                                  nullptr, nullptr, bmTri, cmpOff,
                                                  triEmb, NT);

    // ---- stage B: tetAgg = mean_tt(triEmb) compact; tetEmb; tetProj ----
    k_gather<1><<<(NTET + 7) / 8, 256, 0, stream>>>(triEmb, sortedAll, rowOffAll + NT,
                                                    nullptr, nullptr, nullptr, bmTet,
                                                    cmpOff, tetAgg, NTET);
    dim3 gT((NTET + 127) / 128, 2);
    k_gemm_mfma<false, true, true, true><<<gT, 256, 0, stream>>>(
        tetAgg, W3b, lin3_b, tetEmb, NTET, cmpOff);
    k_gemm_mfma<false, false, true, true><<<gT, 256, 0, stream>>>(
        tetEmb, Wtb, t2e_b, tetProj, NTET, cmpOff);

    // ---- stage C: V = w0*E + w1*mean_etet(tetProj[cmp])  [needEnt only] ----
    k_gather<2><<<(NE + 7) / 8, 256, 0, stream>>>(tetProj, sortedAll,
                                                  rowOffAll + NT + NTET, nullptr,
                                                  E, alpha, bmEnt, cmpOff, V, NE);

    // ---- stage D: TransE scores ----
    k_score<<<(B + 3) / 4, 256, 0, stream>>>(V, R, trip, gamma, (float*)d_out, B);
}